// Round 5
// baseline (788.505 us; speedup 1.0000x reference)
//
#include <hip/hip_runtime.h>

#define HID 2048
#define NH 16
#define DH 128
#define DFF 8192
#define BB 2
#define TT 2048
#define MROWS 4096   // B*T

typedef __bf16 bf16x8 __attribute__((ext_vector_type(8)));
typedef __bf16 bf16x4 __attribute__((ext_vector_type(4)));
typedef float  f32x4  __attribute__((ext_vector_type(4)));

__device__ __forceinline__ f32x4 mfma16(bf16x8 a, bf16x8 b, f32x4 c) {
    return __builtin_amdgcn_mfma_f32_16x16x32_bf16(a, b, c, 0, 0, 0);
}

__device__ __forceinline__ void gload_lds16(const __bf16* gsrc, __bf16* ldst) {
    __builtin_amdgcn_global_load_lds(
        (const __attribute__((address_space(1))) void*)gsrc,
        (__attribute__((address_space(3))) void*)ldst, 16, 0, 0);
}

// ---------------- weight transpose+convert: W[K][N] f32 -> Wt[N][K] bf16 ----
template<int K, int N>
__global__ __launch_bounds__(256) void transpose_bf16_kernel(
    const float* __restrict__ W, __bf16* __restrict__ Wt) {
    __shared__ float tile[64][65];
    int tx = threadIdx.x;
    int ty = threadIdx.y;
    int n0 = blockIdx.x * 64;
    int k0 = blockIdx.y * 64;
    #pragma unroll
    for (int i = 0; i < 16; i++) {
        int kk = ty * 16 + i;
        tile[tx][kk] = W[(size_t)(k0 + kk) * N + n0 + tx];
    }
    __syncthreads();
    #pragma unroll
    for (int i = 0; i < 16; i++) {
        int nn = ty * 16 + i;
        Wt[(size_t)(n0 + nn) * K + k0 + tx] = (__bf16)tile[nn][tx];
    }
}

// ---------------- LayerNorm f32 -> bf16 ------------------------------------
__global__ __launch_bounds__(256) void ln_kernel(
    const float* __restrict__ x, const float* __restrict__ gw,
    const float* __restrict__ gb, __bf16* __restrict__ out) {
    int row = blockIdx.x;
    int t = threadIdx.x;
    const float* xr = x + (size_t)row * HID;
    float4 v0 = *(const float4*)(xr + t * 8);
    float4 v1 = *(const float4*)(xr + t * 8 + 4);
    float xv[8] = {v0.x, v0.y, v0.z, v0.w, v1.x, v1.y, v1.z, v1.w};
    float s = 0.f, q = 0.f;
    #pragma unroll
    for (int j = 0; j < 8; j++) { s += xv[j]; q += xv[j] * xv[j]; }
    #pragma unroll
    for (int off = 1; off < 64; off <<= 1) {
        s += __shfl_xor(s, off);
        q += __shfl_xor(q, off);
    }
    __shared__ float ssum[4], ssq[4];
    if ((t & 63) == 0) { ssum[t >> 6] = s; ssq[t >> 6] = q; }
    __syncthreads();
    s = ssum[0] + ssum[1] + ssum[2] + ssum[3];
    q = ssq[0] + ssq[1] + ssq[2] + ssq[3];
    float mu = s * (1.0f / HID);
    float var = q * (1.0f / HID) - mu * mu;
    float rs = rsqrtf(var + 1e-5f);
    bf16x8 o;
    #pragma unroll
    for (int j = 0; j < 8; j++)
        o[j] = (__bf16)((xv[j] - mu) * rs * gw[t * 8 + j] + gb[t * 8 + j]);
    *(bf16x8*)(out + (size_t)row * HID + t * 8) = o;
}

// ---------------- init kernel for MLP2 atomic accumulation ------------------
__global__ __launch_bounds__(256) void init_out_kernel(
    const float* __restrict__ x1, const float* __restrict__ b2,
    float* __restrict__ out) {
    int i = blockIdx.x * 256 + threadIdx.x;
    float4 a = ((const float4*)x1)[i];
    float4 bb = ((const float4*)b2)[i & (HID / 4 - 1)];
    float4 o = {a.x + bb.x, a.y + bb.y, a.z + bb.z, a.w + bb.w};
    ((float4*)out)[i] = o;
}

// ---------------- 256x256 8-phase GEMM (m201 structure) ---------------------
// Sync invariant: every LDS region write is issued only after a barrier that
// follows all waves' lgkmcnt(0) drain of reads from that region; every read
// follows a barrier that follows ALL waves' covering vmcnt (vmcnt BEFORE the
// barrier — a wave's vmcnt says nothing about other waves' staging loads).
// EPI: 2=f32 +resid, 3=bf16 silu(+bias), 5=f32 atomicAdd (K-split),
//      6=QKV split (C0=q bf16, C1=k bf16, C2=v transposed [B,NH,DH,T])
template<int EPI, int KSPLIT, int N, int K>
__global__ __launch_bounds__(512, 2) void gemm256(
    const __bf16* __restrict__ A, const __bf16* __restrict__ Bt,
    void* __restrict__ C0, void* __restrict__ C1, void* __restrict__ C2,
    const float* __restrict__ resid, const float* __restrict__ bias, int nN) {
    constexpr int BK = 64;
    constexpr int KS = K / KSPLIT;
    constexpr int NT = KS / BK;

    __shared__ __align__(16) __bf16 As[2][16384];   // [dbuf][256 rows x 64]
    __shared__ __align__(16) __bf16 Bs[2][16384];

    int tid = threadIdx.x;
    int w = tid >> 6, l = tid & 63;
    int wm = w >> 2, wn = w & 3;
    int qi = l & 15, g = l >> 4;

    int nwg = gridDim.x;
    int bid = blockIdx.x;
    int wg = (bid & 7) * (nwg >> 3) + (bid >> 3);   // XCD swizzle (nwg%8==0)
    int nMN = nwg / KSPLIT;
    int tileid = wg % nMN;
    int kh = wg / nMN;
    int bm = tileid / nN, bn = tileid % nN;
    int row0 = bm * 256, col0 = bn * 256;
    int kb0 = kh * KS;

    // staging source offsets (pre-swizzled chunk, rule #21)
    int offA[2][2], offB[2][2];
    #pragma unroll
    for (int h = 0; h < 2; h++)
        #pragma unroll
        for (int i = 0; i < 2; i++) {
            int slot = i * 512 + tid;
            int r = slot >> 3, u8 = slot & 7;
            offA[h][i] = (row0 + h * 128 + r) * K + kb0 + (u8 ^ (r & 7)) * 8;
            offB[h][i] = (col0 + h * 128 + r) * K + kb0 + (u8 ^ (r & 7)) * 8;
        }
    int dstoff = w * 512;   // + i*4096 + h*8192 (elements)

    f32x4 acc[8][4] = {};
    bf16x8 aF[4][2], bF0[2][2], bF1[2][2];

    auto stageA = [&](int u, int h) {
        #pragma unroll
        for (int i = 0; i < 2; i++)
            gload_lds16(A + offA[h][i] + u * BK,
                        &As[u & 1][h * 8192 + i * 4096 + dstoff]);
    };
    auto stageB = [&](int u, int h) {
        #pragma unroll
        for (int i = 0; i < 2; i++)
            gload_lds16(Bt + offB[h][i] + u * BK,
                        &Bs[u & 1][h * 8192 + i * 4096 + dstoff]);
    };
    auto loadA = [&](int s, int qm) {
        #pragma unroll
        for (int mi = 0; mi < 4; mi++) {
            int rA = qm * 128 + wm * 64 + mi * 16 + qi;
            #pragma unroll
            for (int kk = 0; kk < 2; kk++) {
                int byt = rA * 128 + ((kk * 64 + g * 16) ^ ((rA & 7) << 4));
                aF[mi][kk] = *(const bf16x8*)((const char*)As[s] + byt);
            }
        }
    };
    auto loadB = [&](bf16x8 (&bF)[2][2], int s, int qn) {
        #pragma unroll
        for (int ni = 0; ni < 2; ni++) {
            int rB = qn * 128 + wn * 32 + ni * 16 + qi;
            #pragma unroll
            for (int kk = 0; kk < 2; kk++) {
                int byt = rB * 128 + ((kk * 64 + g * 16) ^ ((rB & 7) << 4));
                bF[ni][kk] = *(const bf16x8*)((const char*)Bs[s] + byt);
            }
        }
    };

    #define MMAC(BF, FMB, FNB)                                             \
        asm volatile("s_waitcnt lgkmcnt(0)" ::: "memory");                 \
        __builtin_amdgcn_sched_barrier(0);                                 \
        __builtin_amdgcn_s_setprio(1);                                     \
        _Pragma("unroll")                                                  \
        for (int kk = 0; kk < 2; kk++)                                     \
            _Pragma("unroll")                                              \
            for (int mi = 0; mi < 4; mi++)                                 \
                _Pragma("unroll")                                          \
                for (int ni = 0; ni < 2; ni++)                             \
                    acc[(FMB) + mi][(FNB) + ni] =                          \
                        mfma16(aF[mi][kk], BF[ni][kk],                     \
                               acc[(FMB) + mi][(FNB) + ni]);               \
        __builtin_amdgcn_s_setprio(0);

    // prologue: stage half-tiles = tile0{A0,B0,A1,B1} tile1{A0,B0,A1},
    // then vmcnt(6) [tile0's 8 loads drained] BEFORE a barrier (invariant).
    stageA(0, 0); stageB(0, 0); stageA(0, 1); stageB(0, 1);
    if (NT > 1) { stageA(1, 0); stageB(1, 0); stageA(1, 1); }
    asm volatile("s_waitcnt vmcnt(6)" ::: "memory");
    __builtin_amdgcn_s_barrier();

    for (int t = 0; t < NT; t++) {
        int s = t & 1;
        // phase 0: quadrant (A0,B0); stage (t+1).B1
        loadA(s, 0); loadB(bF0, s, 0);
        if (t + 1 < NT) stageB(t + 1, 1);
        __builtin_amdgcn_s_barrier();
        MMAC(bF0, 0, 0)
        __builtin_amdgcn_s_barrier();
        // phase 1: quadrant (A0,B1); stage (t+2).A0
        loadB(bF1, s, 1);
        if (t + 2 < NT) stageA(t + 2, 0);
        __builtin_amdgcn_s_barrier();
        MMAC(bF1, 0, 2)
        __builtin_amdgcn_s_barrier();
        // phase 2: quadrant (A1,B0); stage (t+2).B0
        loadA(s, 1);
        if (t + 2 < NT) stageB(t + 2, 0);
        __builtin_amdgcn_s_barrier();
        MMAC(bF0, 4, 0)
        __builtin_amdgcn_s_barrier();
        // phase 3: quadrant (A1,B1); stage (t+2).A1
        if (t + 2 < NT) stageA(t + 2, 1);
        __builtin_amdgcn_s_barrier();
        MMAC(bF1, 4, 2)
        // end-of-iteration: drain so tile t+1 is fully landed, BEFORE the
        // final barrier (all waves drain, then barrier, then anyone reads).
        if (t + 2 < NT)      asm volatile("s_waitcnt vmcnt(6)" ::: "memory");
        else if (t + 1 < NT) asm volatile("s_waitcnt vmcnt(0)" ::: "memory");
        __builtin_amdgcn_s_barrier();
    }
    #undef MMAC

    // epilogue: D layout col=lane&15, row=(lane>>4)*4+r
    #pragma unroll
    for (int fm = 0; fm < 8; fm++) {
        int qm = fm >> 2, mi = fm & 3;
        int Rb = row0 + qm * 128 + wm * 64 + mi * 16 + g * 4;
        #pragma unroll
        for (int fn = 0; fn < 4; fn++) {
            int qn = fn >> 1, ni = fn & 1;
            int C = col0 + qn * 128 + wn * 32 + ni * 16 + qi;
            f32x4 v = acc[fm][fn];
            if constexpr (EPI == 6) {
                int region = C >> 11;
                int Cl = C & 2047;
                if (region < 2) {
                    __bf16* dst = (__bf16*)(region == 0 ? C0 : C1);
                    #pragma unroll
                    for (int r = 0; r < 4; r++)
                        dst[(size_t)(Rb + r) * 2048 + Cl] = (__bf16)v[r];
                } else {
                    bf16x4 pk;
                    #pragma unroll
                    for (int r = 0; r < 4; r++) pk[r] = (__bf16)v[r];
                    int b = Rb >> 11, t0 = Rb & 2047, hh = Cl >> 7, d = Cl & 127;
                    *(bf16x4*)((__bf16*)C2 +
                        ((size_t)(b * NH + hh) * DH + d) * TT + t0) = pk;
                }
            } else {
                #pragma unroll
                for (int r = 0; r < 4; r++) {
                    size_t idx = (size_t)(Rb + r) * N + C;
                    if constexpr (EPI == 2) {
                        ((float*)C0)[idx] = resid[idx] + v[r];
                    } else if constexpr (EPI == 3) {
                        float u = v[r] + bias[C];
                        ((__bf16*)C0)[idx] = (__bf16)(u / (1.f + __expf(-u)));
                    } else if constexpr (EPI == 5) {
                        atomicAdd((float*)C0 + idx, v[r]);
                    }
                }
            }
        }
    }
}

// ---------------- flash attention, KVBLK=64 LDS-staged + XOR swizzle --------
__global__ __launch_bounds__(256) void attn_kernel(
    const __bf16* __restrict__ qh, const __bf16* __restrict__ kh,
    const __bf16* __restrict__ vt, __bf16* __restrict__ out) {
    __shared__ __align__(16) __bf16 Ks[64 * 128];
    __shared__ __align__(16) __bf16 Vts[128 * 64];
    __shared__ __align__(16) __bf16 plds[4][1024];
    int tid = threadIdx.x;
    int w = tid >> 6, l = tid & 63;
    int qi = l & 15, g = l >> 4;
    int bh = blockIdx.y;
    int b = bh >> 4, hd = bh & 15;
    int qtile = gridDim.x - 1 - blockIdx.x;
    int qbase = qtile * 64 + w * 16;
    int qg = qbase + qi;

    const __bf16* qrow = qh + ((size_t)b * TT + qg) * HID + hd * DH;
    const __bf16* kbase = kh + (size_t)b * TT * HID + hd * DH;
    const __bf16* vtb = vt + (size_t)bh * DH * TT;

    bf16x8 bq[4];
    #pragma unroll
    for (int kc = 0; kc < 4; kc++)
        bq[kc] = *(const bf16x8*)(qrow + kc * 32 + g * 8);

    f32x4 O[8] = {};
    float m_run = -3.0e38f, l_run = 0.f;
    const float scale = 0.08838834764831845f;
    int nt = qtile + 1;

    for (int it = 0; it < nt; it++) {
        int kv0 = it * 64;
        __syncthreads();
        #pragma unroll
        for (int i = 0; i < 4; i++) {
            int j = (w * 4 + i) * 64 + l;
            int r = j >> 4, u = j & 15;
            int cb = (u * 16) ^ ((r & 7) << 4);
            gload_lds16(kbase + (size_t)(kv0 + r) * HID + (cb >> 1),
                        Ks + (w * 4 + i) * 512);
        }
        #pragma unroll
        for (int i = 0; i < 4; i++) {
            int j = (w * 4 + i) * 64 + l;
            int r = j >> 3, u = j & 7;
            int cb = (u * 16) ^ ((r & 7) << 4);
            gload_lds16(vtb + (size_t)r * TT + kv0 + (cb >> 1),
                        Vts + (w * 4 + i) * 512);
        }
        __syncthreads();

        f32x4 st[4] = {};
        #pragma unroll
        for (int t = 0; t < 4; t++) {
            #pragma unroll
            for (int kc = 0; kc < 4; kc++) {
                int row = t * 16 + qi;
                int cb = (kc * 64 + g * 16) ^ ((qi & 7) << 4);
                bf16x8 ak = *(const bf16x8*)(Ks + row * 128 + (cb >> 1));
                st[t] = mfma16(ak, bq[kc], st[t]);
            }
        }
        float s[16];
        #pragma unroll
        for (int t = 0; t < 4; t++)
            #pragma unroll
            for (int r = 0; r < 4; r++) s[t * 4 + r] = st[t][r] * scale;
        #pragma unroll
        for (int i = 0; i < 16; i++) {
            int kvg = kv0 + (i >> 2) * 16 + g * 4 + (i & 3);
            if (kvg > qg) s[i] = -3.0e38f;
        }
        float mt = s[0];
        #pragma unroll
        for (int i = 1; i < 16; i++) mt = fmaxf(mt, s[i]);
        mt = fmaxf(mt, __shfl_xor(mt, 16));
        mt = fmaxf(mt, __shfl_xor(mt, 32));
        float m_new = fmaxf(m_run, mt);
        float alpha = __expf(m_run - m_new);
        float p[16], ps = 0.f;
        #pragma unroll
        for (int i = 0; i < 16; i++) { p[i] = __expf(s[i] - m_new); ps += p[i]; }
        ps += __shfl_xor(ps, 16);
        ps += __shfl_xor(ps, 32);
        l_run = l_run * alpha + ps;
        m_run = m_new;

        #pragma unroll
        for (int t = 0; t < 4; t++) {
            bf16x4 pk;
            #pragma unroll
            for (int r = 0; r < 4; r++) pk[r] = (__bf16)p[t * 4 + r];
            int cb = (t * 32 + g * 8) ^ ((qi & 7) << 4);
            *(bf16x4*)(&plds[w][qi * 64 + (cb >> 1)]) = pk;
        }

        float av[4];
        #pragma unroll
        for (int r = 0; r < 4; r++) av[r] = __shfl(alpha, (g << 4) | (g * 4 + r));
        #pragma unroll
        for (int oc = 0; oc < 8; oc++)
            #pragma unroll
            for (int r = 0; r < 4; r++) O[oc][r] *= av[r];

        #pragma unroll
        for (int h = 0; h < 2; h++) {
            int cbp = (h * 64 + g * 16) ^ ((qi & 7) << 4);
            bf16x8 ap = *(const bf16x8*)(&plds[w][qi * 64 + (cbp >> 1)]);
            #pragma unroll
            for (int oc = 0; oc < 8; oc++) {
                int row = oc * 16 + qi;
                int cb = (h * 64 + g * 16) ^ ((qi & 7) << 4);
                bf16x8 bv = *(const bf16x8*)(Vts + row * 64 + (cb >> 1));
                O[oc] = mfma16(ap, bv, O[oc]);
            }
        }
    }

    float linv[4];
    #pragma unroll
    for (int r = 0; r < 4; r++) {
        float lq = __shfl(l_run, (g << 4) | (g * 4 + r));
        linv[r] = 1.0f / lq;
    }
    __bf16* op = out + ((size_t)b * TT + qbase) * HID + hd * DH;
    #pragma unroll
    for (int oc = 0; oc < 8; oc++)
        #pragma unroll
        for (int r = 0; r < 4; r++)
            op[(size_t)(g * 4 + r) * HID + oc * 16 + qi] = (__bf16)(O[oc][r] * linv[r]);
}

// ---------------- launch ----------------------------------------------------
extern "C" void kernel_launch(void* const* d_in, const int* in_sizes, int n_in,
                              void* d_out, int out_size, void* d_ws, size_t ws_size,
                              hipStream_t stream) {
    const float* x    = (const float*)d_in[0];
    const float* Wq   = (const float*)d_in[2];
    const float* Wk   = (const float*)d_in[3];
    const float* Wv   = (const float*)d_in[4];
    const float* Wo   = (const float*)d_in[5];
    const float* ln1w = (const float*)d_in[6];
    const float* ln1b = (const float*)d_in[7];
    const float* ln2w = (const float*)d_in[8];
    const float* ln2b = (const float*)d_in[9];
    const float* W1   = (const float*)d_in[10];
    const float* b1   = (const float*)d_in[11];
    const float* W2   = (const float*)d_in[12];
    const float* b2   = (const float*)d_in[13];
    float* outp = (float*)d_out;

    char* ws = (char*)d_ws;
    const size_t SZ_W   = (size_t)HID * HID * 2;
    const size_t SZ_WF  = (size_t)HID * DFF * 2;
    const size_t SZ_ACT = (size_t)MROWS * HID * 2;
    const size_t SZ_X32 = (size_t)MROWS * HID * 4;

    __bf16* wqT  = (__bf16*)(ws);                   // wq|wk|wv contiguous
    __bf16* wkT  = (__bf16*)(ws + SZ_W);
    __bf16* wvT  = (__bf16*)(ws + 2 * SZ_W);
    __bf16* woT  = (__bf16*)(ws + 3 * SZ_W);
    __bf16* w1T  = (__bf16*)(ws + 4 * SZ_W);
    __bf16* w2T  = (__bf16*)(ws + 4 * SZ_W + SZ_WF);
    __bf16* h    = (__bf16*)(ws + 4 * SZ_W + 2 * SZ_WF);
    float*  x1   = (float*) (ws + 4 * SZ_W + 2 * SZ_WF + SZ_ACT);
    char*   base = ws + 4 * SZ_W + 2 * SZ_WF + SZ_ACT + SZ_X32;
    __bf16* qb   = (__bf16*)(base);
    __bf16* kb   = (__bf16*)(base + SZ_ACT);
    __bf16* vtb  = (__bf16*)(base + 2 * SZ_ACT);
    __bf16* attn = (__bf16*)(base + 3 * SZ_ACT);
    __bf16* mlp1 = (__bf16*)(base);                  // aliases q/k/vt/attn

    dim3 blk256(256), blk512(512);
    transpose_bf16_kernel<HID, HID><<<dim3(32, 32), dim3(64, 4), 0, stream>>>(Wq, wqT);
    transpose_bf16_kernel<HID, HID><<<dim3(32, 32), dim3(64, 4), 0, stream>>>(Wk, wkT);
    transpose_bf16_kernel<HID, HID><<<dim3(32, 32), dim3(64, 4), 0, stream>>>(Wv, wvT);
    transpose_bf16_kernel<HID, HID><<<dim3(32, 32), dim3(64, 4), 0, stream>>>(Wo, woT);
    transpose_bf16_kernel<HID, DFF><<<dim3(128, 32), dim3(64, 4), 0, stream>>>(W1, w1T);
    transpose_bf16_kernel<DFF, HID><<<dim3(32, 128), dim3(64, 4), 0, stream>>>(W2, w2T);

    ln_kernel<<<MROWS, blk256, 0, stream>>>(x, ln1w, ln1b, h);

    // fused QKV: N=6144 -> 16x24 = 384 blocks
    gemm256<6, 1, 6144, HID><<<384, blk512, 0, stream>>>(
        h, wqT, qb, kb, vtb, nullptr, nullptr, 24);

    attn_kernel<<<dim3(TT / 64, BB * NH), blk256, 0, stream>>>(qb, kb, vtb, attn);

    // O projection + residual: 16x8 = 128 blocks
    gemm256<2, 1, HID, HID><<<128, blk512, 0, stream>>>(
        attn, woT, x1, nullptr, nullptr, x, nullptr, 8);

    ln_kernel<<<MROWS, blk256, 0, stream>>>(x1, ln2w, ln2b, h);

    // MLP1: N=8192 -> 16x32 = 512 blocks
    gemm256<3, 1, DFF, HID><<<512, blk512, 0, stream>>>(
        h, w1T, mlp1, nullptr, nullptr, nullptr, b1, 32);

    // MLP2: init out = x1 + b2, then 2-way K-split atomic GEMM (256 blocks)
    init_out_kernel<<<MROWS * HID / 4 / 256, blk256, 0, stream>>>(x1, b2, outp);
    gemm256<5, 2, HID, DFF><<<256, blk512, 0, stream>>>(
        mlp1, w2T, outp, nullptr, nullptr, nullptr, nullptr, 8);
}